// Round 11
// baseline (336.425 us; speedup 1.0000x reference)
//
#include <hip/hip_runtime.h>
#include <math.h>

#define N_NODES 50000
#define N_EDGES 800000
#define IN_DIM  512
#define HID     128
#define OUT_DIM 64
#define EPS     0.3f

#define SCAN_BLOCKS 49   // ceil(50000 / 1024)
#define LDS_ROW_H 260    // 256 + 4 dword pad (half-K staging row)

typedef __attribute__((ext_vector_type(8))) short bf16x8;
typedef __attribute__((ext_vector_type(8))) __bf16 bf16v8;
typedef __attribute__((ext_vector_type(4))) float f32x4;
typedef __attribute__((ext_vector_type(4))) unsigned int u32x4;

__device__ __forceinline__ float fast_tanh(float x) {
    // tanh(x) = 1 - 2/(exp(2x)+1); saturates correctly at +/-inf
    return 1.0f - 2.0f / (__expf(2.0f * x) + 1.0f);
}

// f32 -> bf16 via native cast: compiler emits v_cvt_pk_bf16_f32 (RNE).
__device__ __forceinline__ unsigned short f2bfu(float f) {
    return __builtin_bit_cast(unsigned short, (__bf16)f);
}
__device__ __forceinline__ unsigned pk2(float lo, float hi) {
    return (unsigned)f2bfu(lo) | ((unsigned)f2bfu(hi) << 16);
}
__device__ __forceinline__ float bf_lo(unsigned u) { return __uint_as_float(u << 16); }
__device__ __forceinline__ float bf_hi(unsigned u) { return __uint_as_float(u & 0xffff0000u); }

// nt store of a 16B packed value (lines land CLEAN at the memory side -> later
// random gathers from other XCDs hit L3 instead of remote-dirty-L2).
__device__ __forceinline__ void nt_store16(void* p, uint4 v) {
    __builtin_nontemporal_store(__builtin_bit_cast(u32x4, v), (u32x4*)p);
}

// degree recovered from input d = rsqrt(deg+1): deg = round(1/d^2) - 1.
__device__ __forceinline__ int deg_of(float dv) {
    return (int)(1.0f / (dv * dv) + 0.5f) - 1;
}

// ---------------- hw: [blk 0..48] degree partials | [49..80] W pack ----------
// R9-proven two-dispatch prep (R10's merged self-sufficient scan cost more
// than the dispatch gap it saved -> reverted). R8 lesson: NEVER one-block
// serial scans (58us).

__global__ void hw_k(const float* __restrict__ d, int* __restrict__ partials,
                     const float* __restrict__ w, unsigned short* __restrict__ wb) {
    int bid = blockIdx.x, tid = threadIdx.x;

    if (bid < SCAN_BLOCKS) {
        int base = bid * 1024 + tid * 4;
        int s = 0;
#pragma unroll
        for (int j = 0; j < 4; j++) if (base + j < N_NODES) s += deg_of(d[base + j]);
#pragma unroll
        for (int off = 32; off; off >>= 1) s += __shfl_down(s, off);
        __shared__ int ws[4];
        int lane = tid & 63, wv = tid >> 6;
        if (lane == 0) ws[wv] = s;
        __syncthreads();
        if (tid == 0) partials[bid] = ws[0] + ws[1] + ws[2] + ws[3];
        return;
    }

    // ---- W pack: MFMA B-fragment order (blocks 49..80, 8192 jobs) ----
    int t = (bid - SCAN_BLOCKS) * 256 + tid;
    int lane = t & 63;
    int ct   = (t >> 6) & 7;
    int ks   = t >> 9;
    int row  = ct * 16 + (lane & 15);
    int kb   = ks * 32 + (lane >> 4) * 8;
    const float* p = &w[(size_t)row * IN_DIM + kb];
    float4 v0 = *(const float4*)p, v1 = *(const float4*)(p + 4);
    uint4 pk;
    pk.x = pk2(v0.x, v0.y);
    pk.y = pk2(v0.z, v0.w);
    pk.z = pk2(v1.x, v1.y);
    pk.w = pk2(v1.z, v1.w);
    *(uint4*)&wb[(size_t)t * 8] = pk;
}

// ---------------- scanw: block scan + in-wave block offset -> rowptr/cursor --

__global__ void scanw_k(const float* __restrict__ d, const int* __restrict__ partials,
                        int* __restrict__ rowptr, int* __restrict__ cursor) {
    int tid = threadIdx.x;
    int base = blockIdx.x * 1024 + tid * 4;
    int v[4]; int s = 0;
#pragma unroll
    for (int j = 0; j < 4; j++) {
        v[j] = (base + j < N_NODES) ? deg_of(d[base + j]) : 0;
        s += v[j];
    }
    int lane = tid & 63, wv = tid >> 6;
    int sc = s;
#pragma unroll
    for (int off = 1; off < 64; off <<= 1) {
        int t = __shfl_up(sc, off);
        if (lane >= off) sc += t;
    }
    __shared__ int wtot[4];
    __shared__ int bofs_s;
    if (lane == 63) wtot[wv] = sc;
    // wave 0: block offset = sum of partials[0..blockIdx-1] (blockIdx <= 48 < 64)
    if (tid < 64) {
        int p = (tid < blockIdx.x) ? partials[tid] : 0;
#pragma unroll
        for (int off = 32; off; off >>= 1) p += __shfl_down(p, off);
        if (tid == 0) bofs_s = p;
    }
    __syncthreads();
    int wof = 0;
    for (int w = 0; w < wv; w++) wof += wtot[w];
    int excl = bofs_s + wof + (sc - s);
#pragma unroll
    for (int j = 0; j < 4; j++) {
        if (base + j < N_NODES) { rowptr[base + j] = excl; cursor[base + j] = excl; }
        excl += v[j];
    }
    if (blockIdx.x == SCAN_BLOCKS - 1 && tid == 0)
        rowptr[N_NODES] = bofs_s + wtot[0] + wtot[1] + wtot[2] + wtot[3];
}

// ---------------- fused t1 (2-phase MFMA tile) | fill (CSR scatter) ----------
// R10-proven 2-phase staging (16.6KB LDS, t1fill 91->84us). fill remains a
// ~56us device-atomic-rate floor. csr/xb0/gd0/gs0 written NONTEMPORAL so
// agg's random gathers see clean L3 lines, not remote-dirty per-XCD L2.

__launch_bounds__(256)
__global__ void t1fill_k(const float* __restrict__ h, const unsigned short* __restrict__ wb,
                         const float* __restrict__ bias, const float* __restrict__ gw0,
                         unsigned short* __restrict__ xb0,
                         float* __restrict__ gd0, float* __restrict__ gs0,
                         const int* __restrict__ src, const int* __restrict__ dst,
                         const int* __restrict__ yn, int* __restrict__ cursor,
                         int* __restrict__ csr) {
    __shared__ float At[16 * LDS_ROW_H];    // 16.6 KB half-K staging buffer
    __shared__ float red[4][4][4][2];       // gate partials [wave][quad][r][pd|ps]

    if (blockIdx.x & 1) {
        // ---- fill half: block (blockIdx>>1), one edge per thread ----
        int e = (blockIdx.x >> 1) * 256 + threadIdx.x;   // < 800000 exactly
        int dv = dst[e];
        int pos = atomicAdd(&cursor[dv], 1);
        __builtin_nontemporal_store(src[e] | (yn[e] << 31), &csr[pos]);
        return;
    }

    // ---- t1 half ----
    int tid  = threadIdx.x;
    int lane = tid & 63;
    int wv   = tid >> 6;
    int l15  = lane & 15;
    int quad = lane >> 4;
    int rowb = (blockIdx.x >> 1) * 16;      // 50000 = 3125*16, no tail

    int ct0 = wv * 2;
    const unsigned short* bp = &wb[(size_t)lane * 8];
    const float* arp = &At[l15 * LDS_ROW_H + quad * 8];
    f32x4 acc[2];
    acc[0] = (f32x4){0.f, 0.f, 0.f, 0.f};
    acc[1] = (f32x4){0.f, 0.f, 0.f, 0.f};

#pragma unroll
    for (int ph = 0; ph < 2; ++ph) {
        // stage: 16 chunks of 1KB (chunk = row, half ph), 4 per wave.
#pragma unroll
        for (int i = 0; i < 4; ++i) {
            int row = wv * 4 + i;
            const float* gsrc = &h[(size_t)(rowb + row) * IN_DIM + ph * 256 + lane * 4];
            float* ldst = &At[row * LDS_ROW_H];
            __builtin_amdgcn_global_load_lds(
                (const __attribute__((address_space(1))) unsigned int*)gsrc,
                (__attribute__((address_space(3))) unsigned int*)ldst, 16, 0, 0);
        }
        __syncthreads();    // drains vmcnt -> staged data visible

#pragma unroll 4
        for (int ks = 0; ks < 8; ++ks) {
            int ks_g = ph * 8 + ks;
            float4 a0 = *(const float4*)(arp + ks * 32);
            float4 a1 = *(const float4*)(arp + ks * 32 + 4);
            bf16v8 av;
            av[0] = (__bf16)a0.x; av[1] = (__bf16)a0.y;
            av[2] = (__bf16)a0.z; av[3] = (__bf16)a0.w;
            av[4] = (__bf16)a1.x; av[5] = (__bf16)a1.y;
            av[6] = (__bf16)a1.z; av[7] = (__bf16)a1.w;
            bf16x8 af = __builtin_bit_cast(bf16x8, av);
            bf16x8 b0 = *(const bf16x8*)(bp + (size_t)(ks_g * 8 + ct0) * 512);
            bf16x8 b1 = *(const bf16x8*)(bp + (size_t)(ks_g * 8 + ct0 + 1) * 512);
            acc[0] = __builtin_amdgcn_mfma_f32_16x16x32_bf16(af, b0, acc[0], 0, 0, 0);
            acc[1] = __builtin_amdgcn_mfma_f32_16x16x32_bf16(af, b1, acc[1], 0, 0, 0);
        }
        __syncthreads();    // all waves done reading before next-phase overwrite
    }

    // epilogue: bias+relu, store bf16 (nt), gate partials for this wave's 32 cols
    float pd[4] = {0.f, 0.f, 0.f, 0.f}, ps[4] = {0.f, 0.f, 0.f, 0.f};
#pragma unroll
    for (int ct = 0; ct < 2; ++ct) {
        int o = (ct0 + ct) * 16 + l15;
        float b = bias[o];
        float wd = gw0[o], wsv = gw0[128 + o];
#pragma unroll
        for (int r = 0; r < 4; ++r) {
            float v = acc[ct][r] + b;
            v = v > 0.f ? v : 0.f;
            int node = rowb + quad * 4 + r;
            __builtin_nontemporal_store(f2bfu(v), &xb0[(size_t)node * HID + o]);
            pd[r] += v * wd; ps[r] += v * wsv;
        }
    }
    // reduce over the 16 lanes of l15
#pragma unroll
    for (int m = 1; m < 16; m <<= 1) {
#pragma unroll
        for (int r = 0; r < 4; ++r) {
            pd[r] += __shfl_xor(pd[r], m);
            ps[r] += __shfl_xor(ps[r], m);
        }
    }
    if (l15 == 0) {
#pragma unroll
        for (int r = 0; r < 4; ++r) {
            red[wv][quad][r][0] = pd[r];
            red[wv][quad][r][1] = ps[r];
        }
    }
    __syncthreads();
    // cross-wave sum: 16 rows handled by lanes 0..15 of wave 0
    if (wv == 0 && lane < 16) {
        int q = lane >> 2, r = lane & 3;
        float sd = red[0][q][r][0] + red[1][q][r][0] + red[2][q][r][0] + red[3][q][r][0];
        float ss = red[0][q][r][1] + red[1][q][r][1] + red[2][q][r][1] + red[3][q][r][1];
        __builtin_nontemporal_store(sd, &gd0[rowb + lane]);
        __builtin_nontemporal_store(ss, &gs0[rowb + lane]);
    }
}

// ---------------- aggregation (R4/R9-proven v5) + fused next gate -----
// One wave per dst node. Batch phase: lane e computes coef for edge e0+lane.
// Gather phase: 4 edges/trip, 16 lanes/edge, coef/src broadcast via __shfl,
// depth-2 software pipeline. R2/R3: keep coef inline. R7: do NOT fuse the t2
// GEMV here (register spill). Outputs written NONTEMPORAL (consumed as random
// gathers / by the next kernel from another XCD).

__global__ void agg_k(const unsigned short* __restrict__ xb,
                      const unsigned short* __restrict__ rb,
                      const int* __restrict__ rowptr, const int* __restrict__ csr,
                      const float* __restrict__ d,
                      const float* __restrict__ gd, const float* __restrict__ gs,
                      const float* __restrict__ gb, int layer,
                      const float* __restrict__ yw, const float* __restrict__ nw,
                      const float* __restrict__ gw_next,
                      float* __restrict__ gd_out, float* __restrict__ gs_out,
                      unsigned short* __restrict__ xb_out) {
    int t = blockIdx.x * blockDim.x + threadIdx.x;
    int nid = t >> 6, lane = t & 63;
    if (nid >= N_NODES) return;
    int l15 = lane & 15, eg = lane >> 4;
    float acc[8];
#pragma unroll
    for (int j = 0; j < 8; j++) acc[j] = 0.f;
    if (lane < 16) {
        uint4 rv = *(const uint4*)&rb[(size_t)nid * HID + l15 * 8];
        acc[0] = EPS * bf_lo(rv.x); acc[1] = EPS * bf_hi(rv.x);
        acc[2] = EPS * bf_lo(rv.y); acc[3] = EPS * bf_hi(rv.y);
        acc[4] = EPS * bf_lo(rv.z); acc[5] = EPS * bf_hi(rv.z);
        acc[6] = EPS * bf_lo(rv.w); acc[7] = EPS * bf_hi(rv.w);
    }
    float gdn = gd[nid] + gb[layer];
    float dn  = d[nid];
    float ty  = fast_tanh(yw[0]);
    float tno = fast_tanh(nw[0]);
    int e0 = rowptr[nid], e1 = rowptr[nid + 1];
    for (int b0 = e0; b0 < e1; b0 += 64) {
        int e = b0 + lane;
        float cf = 0.f; int sidx = 0;
        if (e < e1) {
            int p = csr[e];
            int s = p & 0x7fffffff;
            float ynt = (p < 0) ? ty : tno;
            cf = (fast_tanh(gdn + gs[s]) + ynt) * 0.5f * dn * d[s];
            sidx = s;
        }
        int trips = e1 - b0; if (trips > 64) trips = 64;
        // prime trip 0
        float cfA = __shfl(cf, eg);
        int   sA  = __shfl(sidx, eg);
        uint4 vA  = *(const uint4*)&xb[(size_t)sA * HID + l15 * 8];
        for (int t4 = 0; t4 < trips; t4 += 4) {
            // prefetch trip t4+4 (wave-uniform branch; nx <= 63 always)
            float cfB = 0.f; uint4 vB = make_uint4(0, 0, 0, 0);
            if (t4 + 4 < trips) {
                int nx = t4 + 4 + eg;
                cfB = __shfl(cf, nx);
                int sB = __shfl(sidx, nx);
                vB = *(const uint4*)&xb[(size_t)sB * HID + l15 * 8];
            }
            acc[0] += cfA * bf_lo(vA.x); acc[1] += cfA * bf_hi(vA.x);
            acc[2] += cfA * bf_lo(vA.y); acc[3] += cfA * bf_hi(vA.y);
            acc[4] += cfA * bf_lo(vA.z); acc[5] += cfA * bf_hi(vA.z);
            acc[6] += cfA * bf_lo(vA.w); acc[7] += cfA * bf_hi(vA.w);
            cfA = cfB; vA = vB;
        }
    }
    // fold the 4 edge-groups: after this ALL lanes hold the full row chunk for l15
#pragma unroll
    for (int j = 0; j < 8; j++) acc[j] += __shfl_xor(acc[j], 32);
#pragma unroll
    for (int j = 0; j < 8; j++) acc[j] += __shfl_xor(acc[j], 16);
    if (lane < 16) {
        uint4 pk;
        pk.x = pk2(acc[0], acc[1]);
        pk.y = pk2(acc[2], acc[3]);
        pk.z = pk2(acc[4], acc[5]);
        pk.w = pk2(acc[6], acc[7]);
        nt_store16(&xb_out[(size_t)nid * HID + l15 * 8], pk);
    }
    // fused next-layer gate dots (layer 0 only)
    if (gw_next) {
        float pd = 0.f, psv = 0.f;
#pragma unroll
        for (int j = 0; j < 8; j++) {
            int o = l15 * 8 + j;
            pd  += acc[j] * gw_next[o];
            psv += acc[j] * gw_next[128 + o];
        }
#pragma unroll
        for (int m = 1; m < 16; m <<= 1) {
            pd  += __shfl_xor(pd, m);
            psv += __shfl_xor(psv, m);
        }
        if (lane == 0) {
            __builtin_nontemporal_store(pd, &gd_out[nid]);
            __builtin_nontemporal_store(psv, &gs_out[nid]);
        }
    }
}

// ---------------- t2 + log_softmax: 64-node tile per block (bf16 x) ----------------

__launch_bounds__(256)
__global__ void out_k(const unsigned short* __restrict__ xb, const float* __restrict__ w,
                      const float* __restrict__ bias, float* __restrict__ out) {
    __shared__ float As[64][132];   // 64 nodes x 128 k
    __shared__ float Bs[64][132];   // 64 outs  x 128 k
    int tid = threadIdx.x;
    int n0  = blockIdx.x * 64;
#pragma unroll
    for (int j = 0; j < 4; j++) {
        int c8 = tid + j * 256;          // 1024 chunks of 8 bf16
        int r = c8 >> 4, c = (c8 & 15) * 8;
        int gr = n0 + r;
        uint4 v = make_uint4(0, 0, 0, 0);
        if (gr < N_NODES) v = *(const uint4*)&xb[(size_t)gr * HID + c];
        *(float4*)&As[r][c]     = make_float4(bf_lo(v.x), bf_hi(v.x), bf_lo(v.y), bf_hi(v.y));
        *(float4*)&As[r][c + 4] = make_float4(bf_lo(v.z), bf_hi(v.z), bf_lo(v.w), bf_hi(v.w));
    }
#pragma unroll
    for (int j = 0; j < 8; j++) {
        int f4 = tid + j * 256;
        int r = f4 >> 5, c = (f4 & 31) * 4;
        *(float4*)&Bs[r][c] = *(const float4*)&w[r * HID + c];
    }
    __syncthreads();
    int tn = tid >> 4, to = tid & 15;
    float acc[4][4];
#pragma unroll
    for (int i = 0; i < 4; i++)
#pragma unroll
        for (int j = 0; j < 4; j++) acc[i][j] = 0.0f;
    // unroll capped at 2: full unroll was the VGPR=256 spill (R1)
#pragma unroll 2
    for (int k = 0; k < HID; k += 4) {
        float4 av[4], bv[4];
#pragma unroll
        for (int i = 0; i < 4; i++) av[i] = *(const float4*)&As[tn + 16 * i][k];
#pragma unroll
        for (int j = 0; j < 4; j++) bv[j] = *(const float4*)&Bs[to + 16 * j][k];
#pragma unroll
        for (int i = 0; i < 4; i++)
#pragma unroll
            for (int j = 0; j < 4; j++) {
                acc[i][j] += av[i].x * bv[j].x;
                acc[i][j] += av[i].y * bv[j].y;
                acc[i][j] += av[i].z * bv[j].z;
                acc[i][j] += av[i].w * bv[j].w;
            }
    }
    float bj[4];
#pragma unroll
    for (int j = 0; j < 4; j++) bj[j] = bias[to + 16 * j];
#pragma unroll
    for (int i = 0; i < 4; i++) {
        float v[4];
        float m = -1e30f;
#pragma unroll
        for (int j = 0; j < 4; j++) { v[j] = acc[i][j] + bj[j]; m = fmaxf(m, v[j]); }
#pragma unroll
        for (int s = 1; s < 16; s <<= 1) m = fmaxf(m, __shfl_xor(m, s));
        float sum = 0.f;
#pragma unroll
        for (int j = 0; j < 4; j++) sum += __expf(v[j] - m);
#pragma unroll
        for (int s = 1; s < 16; s <<= 1) sum += __shfl_xor(sum, s);
        float lse = m + __logf(sum);
        int r = n0 + tn + 16 * i;
        if (r < N_NODES) {
#pragma unroll
            for (int j = 0; j < 4; j++) out[r * OUT_DIM + to + 16 * j] = v[j] - lse;
        }
    }
}

// ---------------- launcher ----------------

extern "C" void kernel_launch(void* const* d_in, const int* in_sizes, int n_in,
                              void* d_out, int out_size, void* d_ws, size_t ws_size,
                              hipStream_t stream) {
    const float* h    = (const float*)d_in[0];
    const float* d    = (const float*)d_in[1];
    const float* t1_w = (const float*)d_in[2];
    const float* t1_b = (const float*)d_in[3];
    const float* gw   = (const float*)d_in[4];   // [2][256]
    const float* gb   = (const float*)d_in[5];   // [2]
    const float* t2_w = (const float*)d_in[6];   // [64][128]
    const float* t2_b = (const float*)d_in[7];
    const float* yw   = (const float*)d_in[8];
    const float* nw   = (const float*)d_in[9];
    const int* src    = (const int*)d_in[10];
    const int* dst    = (const int*)d_in[11];
    const int* yn     = (const int*)d_in[12];
    float* outp = (float*)d_out;

    char* ws = (char*)d_ws;
    size_t off = 0;
    auto alloc = [&](size_t bytes) {
        void* p = ws + off;
        off = (off + bytes + 255) & ~(size_t)255;
        return p;
    };
    unsigned short* xb0 = (unsigned short*)alloc((size_t)N_NODES * HID * 2);
    unsigned short* xb1 = (unsigned short*)alloc((size_t)N_NODES * HID * 2);
    unsigned short* xb2 = (unsigned short*)alloc((size_t)N_NODES * HID * 2);
    unsigned short* wb  = (unsigned short*)alloc((size_t)8192 * 8 * 2);
    float* gd0    = (float*)alloc((size_t)N_NODES * 4);
    float* gs0    = (float*)alloc((size_t)N_NODES * 4);
    float* gd1    = (float*)alloc((size_t)N_NODES * 4);
    float* gs1    = (float*)alloc((size_t)N_NODES * 4);
    int*   rowptr = (int*)alloc((size_t)(N_NODES + 1) * 4);
    int*   cursor = (int*)alloc((size_t)N_NODES * 4);
    int*   csr    = (int*)alloc((size_t)N_EDGES * 4);
    int*   partials = (int*)alloc(64 * 4);
    (void)ws_size; (void)n_in; (void)in_sizes; (void)out_size;

    // degree partials + W pack (independent, coalesced, parallel; R9-proven)
    hw_k<<<SCAN_BLOCKS + 32, 256, 0, stream>>>(d, partials, t1_w, wb);
    // rowptr/cursor scan (each block derives its own offset from partials)
    scanw_k<<<SCAN_BLOCKS, 256, 0, stream>>>(d, partials, rowptr, cursor);

    // fused t1 | fill (interleaved block types; 2-phase 16.6KB LDS, R10-proven)
    t1fill_k<<<2 * (N_NODES / 16), 256, 0, stream>>>(h, wb, t1_b, gw, xb0, gd0, gs0,
                                                     src, dst, yn, cursor, csr);

    int wave_blocks = (N_NODES * 64 + 255) / 256;   // one wave per node

    // layer 0: gather xb0, residual xb0 -> xb1, fused layer-1 gate dots
    agg_k<<<wave_blocks, 256, 0, stream>>>(xb0, xb0, rowptr, csr, d, gd0, gs0, gb, 0,
                                           yw, nw, gw + 256, gd1, gs1, xb1);
    // layer 1: gather xb1, residual xb0 (raw is FIXED across layers) -> xb2
    agg_k<<<wave_blocks, 256, 0, stream>>>(xb1, xb0, rowptr, csr, d, gd1, gs1, gb, 1,
                                           yw, nw, (const float*)nullptr,
                                           (float*)nullptr, (float*)nullptr, xb2);

    // t2 + log_softmax (bf16 x, R4-proven)
    out_k<<<(N_NODES + 63) / 64, 256, 0, stream>>>(xb2, t2_w, t2_b, outp);
}

// Round 12
// 323.788 us; speedup vs baseline: 1.0390x; 1.0390x over previous
//
#include <hip/hip_runtime.h>
#include <math.h>

#define N_NODES 50000
#define N_EDGES 800000
#define IN_DIM  512
#define HID     128
#define OUT_DIM 64
#define EPS     0.3f

#define SCAN_BLOCKS 49   // ceil(50000 / 1024)
#define LDS_ROW_H 260    // 256 + 4 dword pad (half-K staging row)

typedef __attribute__((ext_vector_type(8))) short bf16x8;
typedef __attribute__((ext_vector_type(8))) __bf16 bf16v8;
typedef __attribute__((ext_vector_type(4))) float f32x4;

__device__ __forceinline__ float fast_tanh(float x) {
    // tanh(x) = 1 - 2/(exp(2x)+1); saturates correctly at +/-inf
    return 1.0f - 2.0f / (__expf(2.0f * x) + 1.0f);
}

// f32 -> bf16 via native cast: compiler emits v_cvt_pk_bf16_f32 (RNE).
__device__ __forceinline__ unsigned short f2bfu(float f) {
    return __builtin_bit_cast(unsigned short, (__bf16)f);
}
__device__ __forceinline__ unsigned pk2(float lo, float hi) {
    return (unsigned)f2bfu(lo) | ((unsigned)f2bfu(hi) << 16);
}
__device__ __forceinline__ float bf_lo(unsigned u) { return __uint_as_float(u << 16); }
__device__ __forceinline__ float bf_hi(unsigned u) { return __uint_as_float(u & 0xffff0000u); }

// degree recovered from input d = rsqrt(deg+1): deg = round(1/d^2) - 1.
__device__ __forceinline__ int deg_of(float dv) {
    return (int)(1.0f / (dv * dv) + 0.5f) - 1;
}

// ---------------- hw: [blk 0..48] degree partials | [49..80] W pack ----------
// R9-proven two-dispatch prep. R8 lesson: NEVER one-block serial scans (58us).
// R10 lesson: merged self-sufficient scan costs more than the gap it saves.
// R11 lesson: nt stores on scattered small writes = +14MB partial-line traffic,
// +5us on t1fill, zero gather-side benefit -> plain stores everywhere.

__global__ void hw_k(const float* __restrict__ d, int* __restrict__ partials,
                     const float* __restrict__ w, unsigned short* __restrict__ wb) {
    int bid = blockIdx.x, tid = threadIdx.x;

    if (bid < SCAN_BLOCKS) {
        int base = bid * 1024 + tid * 4;
        int s = 0;
#pragma unroll
        for (int j = 0; j < 4; j++) if (base + j < N_NODES) s += deg_of(d[base + j]);
#pragma unroll
        for (int off = 32; off; off >>= 1) s += __shfl_down(s, off);
        __shared__ int ws[4];
        int lane = tid & 63, wv = tid >> 6;
        if (lane == 0) ws[wv] = s;
        __syncthreads();
        if (tid == 0) partials[bid] = ws[0] + ws[1] + ws[2] + ws[3];
        return;
    }

    // ---- W pack: MFMA B-fragment order (blocks 49..80, 8192 jobs) ----
    int t = (bid - SCAN_BLOCKS) * 256 + tid;
    int lane = t & 63;
    int ct   = (t >> 6) & 7;
    int ks   = t >> 9;
    int row  = ct * 16 + (lane & 15);
    int kb   = ks * 32 + (lane >> 4) * 8;
    const float* p = &w[(size_t)row * IN_DIM + kb];
    float4 v0 = *(const float4*)p, v1 = *(const float4*)(p + 4);
    uint4 pk;
    pk.x = pk2(v0.x, v0.y);
    pk.y = pk2(v0.z, v0.w);
    pk.z = pk2(v1.x, v1.y);
    pk.w = pk2(v1.z, v1.w);
    *(uint4*)&wb[(size_t)t * 8] = pk;
}

// ---------------- scanw: block scan + in-wave block offset -> rowptr/cursor --

__global__ void scanw_k(const float* __restrict__ d, const int* __restrict__ partials,
                        int* __restrict__ rowptr, int* __restrict__ cursor) {
    int tid = threadIdx.x;
    int base = blockIdx.x * 1024 + tid * 4;
    int v[4]; int s = 0;
#pragma unroll
    for (int j = 0; j < 4; j++) {
        v[j] = (base + j < N_NODES) ? deg_of(d[base + j]) : 0;
        s += v[j];
    }
    int lane = tid & 63, wv = tid >> 6;
    int sc = s;
#pragma unroll
    for (int off = 1; off < 64; off <<= 1) {
        int t = __shfl_up(sc, off);
        if (lane >= off) sc += t;
    }
    __shared__ int wtot[4];
    __shared__ int bofs_s;
    if (lane == 63) wtot[wv] = sc;
    // wave 0: block offset = sum of partials[0..blockIdx-1] (blockIdx <= 48 < 64)
    if (tid < 64) {
        int p = (tid < blockIdx.x) ? partials[tid] : 0;
#pragma unroll
        for (int off = 32; off; off >>= 1) p += __shfl_down(p, off);
        if (tid == 0) bofs_s = p;
    }
    __syncthreads();
    int wof = 0;
    for (int w = 0; w < wv; w++) wof += wtot[w];
    int excl = bofs_s + wof + (sc - s);
#pragma unroll
    for (int j = 0; j < 4; j++) {
        if (base + j < N_NODES) { rowptr[base + j] = excl; cursor[base + j] = excl; }
        excl += v[j];
    }
    if (blockIdx.x == SCAN_BLOCKS - 1 && tid == 0)
        rowptr[N_NODES] = bofs_s + wtot[0] + wtot[1] + wtot[2] + wtot[3];
}

// ---------------- fused t1 (2-phase MFMA tile) | fill (CSR scatter) ----------
// R10-proven 2-phase staging (16.6KB LDS, t1fill 84us measured). fill remains
// a ~56us device-atomic-rate floor (R3/R4/R9: traffic- and occupancy-
// insensitive). Plain stores (R11: nt regressed).

__launch_bounds__(256)
__global__ void t1fill_k(const float* __restrict__ h, const unsigned short* __restrict__ wb,
                         const float* __restrict__ bias, const float* __restrict__ gw0,
                         unsigned short* __restrict__ xb0,
                         float* __restrict__ gd0, float* __restrict__ gs0,
                         const int* __restrict__ src, const int* __restrict__ dst,
                         const int* __restrict__ yn, int* __restrict__ cursor,
                         int* __restrict__ csr) {
    __shared__ float At[16 * LDS_ROW_H];    // 16.6 KB half-K staging buffer
    __shared__ float red[4][4][4][2];       // gate partials [wave][quad][r][pd|ps]

    if (blockIdx.x & 1) {
        // ---- fill half: block (blockIdx>>1), one edge per thread ----
        int e = (blockIdx.x >> 1) * 256 + threadIdx.x;   // < 800000 exactly
        int dv = dst[e];
        int pos = atomicAdd(&cursor[dv], 1);
        csr[pos] = src[e] | (yn[e] << 31);   // src < 2^17, yn packed in sign bit
        return;
    }

    // ---- t1 half ----
    int tid  = threadIdx.x;
    int lane = tid & 63;
    int wv   = tid >> 6;
    int l15  = lane & 15;
    int quad = lane >> 4;
    int rowb = (blockIdx.x >> 1) * 16;      // 50000 = 3125*16, no tail

    int ct0 = wv * 2;
    const unsigned short* bp = &wb[(size_t)lane * 8];
    const float* arp = &At[l15 * LDS_ROW_H + quad * 8];
    f32x4 acc[2];
    acc[0] = (f32x4){0.f, 0.f, 0.f, 0.f};
    acc[1] = (f32x4){0.f, 0.f, 0.f, 0.f};

#pragma unroll
    for (int ph = 0; ph < 2; ++ph) {
        // stage: 16 chunks of 1KB (chunk = row, half ph), 4 per wave.
#pragma unroll
        for (int i = 0; i < 4; ++i) {
            int row = wv * 4 + i;
            const float* gsrc = &h[(size_t)(rowb + row) * IN_DIM + ph * 256 + lane * 4];
            float* ldst = &At[row * LDS_ROW_H];
            __builtin_amdgcn_global_load_lds(
                (const __attribute__((address_space(1))) unsigned int*)gsrc,
                (__attribute__((address_space(3))) unsigned int*)ldst, 16, 0, 0);
        }
        __syncthreads();    // drains vmcnt -> staged data visible

#pragma unroll 4
        for (int ks = 0; ks < 8; ++ks) {
            int ks_g = ph * 8 + ks;
            float4 a0 = *(const float4*)(arp + ks * 32);
            float4 a1 = *(const float4*)(arp + ks * 32 + 4);
            bf16v8 av;
            av[0] = (__bf16)a0.x; av[1] = (__bf16)a0.y;
            av[2] = (__bf16)a0.z; av[3] = (__bf16)a0.w;
            av[4] = (__bf16)a1.x; av[5] = (__bf16)a1.y;
            av[6] = (__bf16)a1.z; av[7] = (__bf16)a1.w;
            bf16x8 af = __builtin_bit_cast(bf16x8, av);
            bf16x8 b0 = *(const bf16x8*)(bp + (size_t)(ks_g * 8 + ct0) * 512);
            bf16x8 b1 = *(const bf16x8*)(bp + (size_t)(ks_g * 8 + ct0 + 1) * 512);
            acc[0] = __builtin_amdgcn_mfma_f32_16x16x32_bf16(af, b0, acc[0], 0, 0, 0);
            acc[1] = __builtin_amdgcn_mfma_f32_16x16x32_bf16(af, b1, acc[1], 0, 0, 0);
        }
        __syncthreads();    // all waves done reading before next-phase overwrite
    }

    // epilogue: bias+relu, store bf16, gate partials for this wave's 32 cols
    float pd[4] = {0.f, 0.f, 0.f, 0.f}, ps[4] = {0.f, 0.f, 0.f, 0.f};
#pragma unroll
    for (int ct = 0; ct < 2; ++ct) {
        int o = (ct0 + ct) * 16 + l15;
        float b = bias[o];
        float wd = gw0[o], wsv = gw0[128 + o];
#pragma unroll
        for (int r = 0; r < 4; ++r) {
            float v = acc[ct][r] + b;
            v = v > 0.f ? v : 0.f;
            int node = rowb + quad * 4 + r;
            xb0[(size_t)node * HID + o] = f2bfu(v);
            pd[r] += v * wd; ps[r] += v * wsv;
        }
    }
    // reduce over the 16 lanes of l15
#pragma unroll
    for (int m = 1; m < 16; m <<= 1) {
#pragma unroll
        for (int r = 0; r < 4; ++r) {
            pd[r] += __shfl_xor(pd[r], m);
            ps[r] += __shfl_xor(ps[r], m);
        }
    }
    if (l15 == 0) {
#pragma unroll
        for (int r = 0; r < 4; ++r) {
            red[wv][quad][r][0] = pd[r];
            red[wv][quad][r][1] = ps[r];
        }
    }
    __syncthreads();
    // cross-wave sum: 16 rows handled by lanes 0..15 of wave 0
    if (wv == 0 && lane < 16) {
        int q = lane >> 2, r = lane & 3;
        float sd = red[0][q][r][0] + red[1][q][r][0] + red[2][q][r][0] + red[3][q][r][0];
        float ss = red[0][q][r][1] + red[1][q][r][1] + red[2][q][r][1] + red[3][q][r][1];
        gd0[rowb + lane] = sd;
        gs0[rowb + lane] = ss;
    }
}

// ---------------- aggregation (R4/R9-proven v5, verbatim) + fused next gate ---
// One wave per dst node. Batch phase: lane e computes coef for edge e0+lane.
// Gather phase: 4 edges/trip, 16 lanes/edge, coef/src broadcast via __shfl,
// depth-2 software pipeline. R2/R3: keep coef inline. R6: separate gd/gs/d
// tables. R7: no t2-GEMV fusion (spill). R11: plain stores.

__global__ void agg_k(const unsigned short* __restrict__ xb,
                      const unsigned short* __restrict__ rb,
                      const int* __restrict__ rowptr, const int* __restrict__ csr,
                      const float* __restrict__ d,
                      const float* __restrict__ gd, const float* __restrict__ gs,
                      const float* __restrict__ gb, int layer,
                      const float* __restrict__ yw, const float* __restrict__ nw,
                      const float* __restrict__ gw_next,
                      float* __restrict__ gd_out, float* __restrict__ gs_out,
                      unsigned short* __restrict__ xb_out) {
    int t = blockIdx.x * blockDim.x + threadIdx.x;
    int nid = t >> 6, lane = t & 63;
    if (nid >= N_NODES) return;
    int l15 = lane & 15, eg = lane >> 4;
    float acc[8];
#pragma unroll
    for (int j = 0; j < 8; j++) acc[j] = 0.f;
    if (lane < 16) {
        uint4 rv = *(const uint4*)&rb[(size_t)nid * HID + l15 * 8];
        acc[0] = EPS * bf_lo(rv.x); acc[1] = EPS * bf_hi(rv.x);
        acc[2] = EPS * bf_lo(rv.y); acc[3] = EPS * bf_hi(rv.y);
        acc[4] = EPS * bf_lo(rv.z); acc[5] = EPS * bf_hi(rv.z);
        acc[6] = EPS * bf_lo(rv.w); acc[7] = EPS * bf_hi(rv.w);
    }
    float gdn = gd[nid] + gb[layer];
    float dn  = d[nid];
    float ty  = fast_tanh(yw[0]);
    float tno = fast_tanh(nw[0]);
    int e0 = rowptr[nid], e1 = rowptr[nid + 1];
    for (int b0 = e0; b0 < e1; b0 += 64) {
        int e = b0 + lane;
        float cf = 0.f; int sidx = 0;
        if (e < e1) {
            int p = csr[e];
            int s = p & 0x7fffffff;
            float ynt = (p < 0) ? ty : tno;
            cf = (fast_tanh(gdn + gs[s]) + ynt) * 0.5f * dn * d[s];
            sidx = s;
        }
        int trips = e1 - b0; if (trips > 64) trips = 64;
        // prime trip 0
        float cfA = __shfl(cf, eg);
        int   sA  = __shfl(sidx, eg);
        uint4 vA  = *(const uint4*)&xb[(size_t)sA * HID + l15 * 8];
        for (int t4 = 0; t4 < trips; t4 += 4) {
            // prefetch trip t4+4 (wave-uniform branch; nx <= 63 always)
            float cfB = 0.f; uint4 vB = make_uint4(0, 0, 0, 0);
            if (t4 + 4 < trips) {
                int nx = t4 + 4 + eg;
                cfB = __shfl(cf, nx);
                int sB = __shfl(sidx, nx);
                vB = *(const uint4*)&xb[(size_t)sB * HID + l15 * 8];
            }
            acc[0] += cfA * bf_lo(vA.x); acc[1] += cfA * bf_hi(vA.x);
            acc[2] += cfA * bf_lo(vA.y); acc[3] += cfA * bf_hi(vA.y);
            acc[4] += cfA * bf_lo(vA.z); acc[5] += cfA * bf_hi(vA.z);
            acc[6] += cfA * bf_lo(vA.w); acc[7] += cfA * bf_hi(vA.w);
            cfA = cfB; vA = vB;
        }
    }
    // fold the 4 edge-groups: after this ALL lanes hold the full row chunk for l15
#pragma unroll
    for (int j = 0; j < 8; j++) acc[j] += __shfl_xor(acc[j], 32);
#pragma unroll
    for (int j = 0; j < 8; j++) acc[j] += __shfl_xor(acc[j], 16);
    if (lane < 16) {
        uint4 pk;
        pk.x = pk2(acc[0], acc[1]);
        pk.y = pk2(acc[2], acc[3]);
        pk.z = pk2(acc[4], acc[5]);
        pk.w = pk2(acc[6], acc[7]);
        *(uint4*)&xb_out[(size_t)nid * HID + l15 * 8] = pk;
    }
    // fused next-layer gate dots (layer 0 only)
    if (gw_next) {
        float pd = 0.f, psv = 0.f;
#pragma unroll
        for (int j = 0; j < 8; j++) {
            int o = l15 * 8 + j;
            pd  += acc[j] * gw_next[o];
            psv += acc[j] * gw_next[128 + o];
        }
#pragma unroll
        for (int m = 1; m < 16; m <<= 1) {
            pd  += __shfl_xor(pd, m);
            psv += __shfl_xor(psv, m);
        }
        if (lane == 0) { gd_out[nid] = pd; gs_out[nid] = psv; }
    }
}

// ---------------- t2 + log_softmax: 64-node tile per block (bf16 x) ----------------

__launch_bounds__(256)
__global__ void out_k(const unsigned short* __restrict__ xb, const float* __restrict__ w,
                      const float* __restrict__ bias, float* __restrict__ out) {
    __shared__ float As[64][132];   // 64 nodes x 128 k
    __shared__ float Bs[64][132];   // 64 outs  x 128 k
    int tid = threadIdx.x;
    int n0  = blockIdx.x * 64;
#pragma unroll
    for (int j = 0; j < 4; j++) {
        int c8 = tid + j * 256;          // 1024 chunks of 8 bf16
        int r = c8 >> 4, c = (c8 & 15) * 8;
        int gr = n0 + r;
        uint4 v = make_uint4(0, 0, 0, 0);
        if (gr < N_NODES) v = *(const uint4*)&xb[(size_t)gr * HID + c];
        *(float4*)&As[r][c]     = make_float4(bf_lo(v.x), bf_hi(v.x), bf_lo(v.y), bf_hi(v.y));
        *(float4*)&As[r][c + 4] = make_float4(bf_lo(v.z), bf_hi(v.z), bf_lo(v.w), bf_hi(v.w));
    }
#pragma unroll
    for (int j = 0; j < 8; j++) {
        int f4 = tid + j * 256;
        int r = f4 >> 5, c = (f4 & 31) * 4;
        *(float4*)&Bs[r][c] = *(const float4*)&w[r * HID + c];
    }
    __syncthreads();
    int tn = tid >> 4, to = tid & 15;
    float acc[4][4];
#pragma unroll
    for (int i = 0; i < 4; i++)
#pragma unroll
        for (int j = 0; j < 4; j++) acc[i][j] = 0.0f;
    // unroll capped at 2: full unroll was the VGPR=256 spill (R1)
#pragma unroll 2
    for (int k = 0; k < HID; k += 4) {
        float4 av[4], bv[4];
#pragma unroll
        for (int i = 0; i < 4; i++) av[i] = *(const float4*)&As[tn + 16 * i][k];
#pragma unroll
        for (int j = 0; j < 4; j++) bv[j] = *(const float4*)&Bs[to + 16 * j][k];
#pragma unroll
        for (int i = 0; i < 4; i++)
#pragma unroll
            for (int j = 0; j < 4; j++) {
                acc[i][j] += av[i].x * bv[j].x;
                acc[i][j] += av[i].y * bv[j].y;
                acc[i][j] += av[i].z * bv[j].z;
                acc[i][j] += av[i].w * bv[j].w;
            }
    }
    float bj[4];
#pragma unroll
    for (int j = 0; j < 4; j++) bj[j] = bias[to + 16 * j];
#pragma unroll
    for (int i = 0; i < 4; i++) {
        float v[4];
        float m = -1e30f;
#pragma unroll
        for (int j = 0; j < 4; j++) { v[j] = acc[i][j] + bj[j]; m = fmaxf(m, v[j]); }
#pragma unroll
        for (int s = 1; s < 16; s <<= 1) m = fmaxf(m, __shfl_xor(m, s));
        float sum = 0.f;
#pragma unroll
        for (int j = 0; j < 4; j++) sum += __expf(v[j] - m);
#pragma unroll
        for (int s = 1; s < 16; s <<= 1) sum += __shfl_xor(sum, s);
        float lse = m + __logf(sum);
        int r = n0 + tn + 16 * i;
        if (r < N_NODES) {
#pragma unroll
            for (int j = 0; j < 4; j++) out[r * OUT_DIM + to + 16 * j] = v[j] - lse;
        }
    }
}

// ---------------- launcher ----------------

extern "C" void kernel_launch(void* const* d_in, const int* in_sizes, int n_in,
                              void* d_out, int out_size, void* d_ws, size_t ws_size,
                              hipStream_t stream) {
    const float* h    = (const float*)d_in[0];
    const float* d    = (const float*)d_in[1];
    const float* t1_w = (const float*)d_in[2];
    const float* t1_b = (const float*)d_in[3];
    const float* gw   = (const float*)d_in[4];   // [2][256]
    const float* gb   = (const float*)d_in[5];   // [2]
    const float* t2_w = (const float*)d_in[6];   // [64][128]
    const float* t2_b = (const float*)d_in[7];
    const float* yw   = (const float*)d_in[8];
    const float* nw   = (const float*)d_in[9];
    const int* src    = (const int*)d_in[10];
    const int* dst    = (const int*)d_in[11];
    const int* yn     = (const int*)d_in[12];
    float* outp = (float*)d_out;

    char* ws = (char*)d_ws;
    size_t off = 0;
    auto alloc = [&](size_t bytes) {
        void* p = ws + off;
        off = (off + bytes + 255) & ~(size_t)255;
        return p;
    };
    unsigned short* xb0 = (unsigned short*)alloc((size_t)N_NODES * HID * 2);
    unsigned short* xb1 = (unsigned short*)alloc((size_t)N_NODES * HID * 2);
    unsigned short* xb2 = (unsigned short*)alloc((size_t)N_NODES * HID * 2);
    unsigned short* wb  = (unsigned short*)alloc((size_t)8192 * 8 * 2);
    float* gd0    = (float*)alloc((size_t)N_NODES * 4);
    float* gs0    = (float*)alloc((size_t)N_NODES * 4);
    float* gd1    = (float*)alloc((size_t)N_NODES * 4);
    float* gs1    = (float*)alloc((size_t)N_NODES * 4);
    int*   rowptr = (int*)alloc((size_t)(N_NODES + 1) * 4);
    int*   cursor = (int*)alloc((size_t)N_NODES * 4);
    int*   csr    = (int*)alloc((size_t)N_EDGES * 4);
    int*   partials = (int*)alloc(64 * 4);
    (void)ws_size; (void)n_in; (void)in_sizes; (void)out_size;

    // degree partials + W pack (independent, coalesced, parallel; R9-proven)
    hw_k<<<SCAN_BLOCKS + 32, 256, 0, stream>>>(d, partials, t1_w, wb);
    // rowptr/cursor scan (each block derives its own offset from partials)
    scanw_k<<<SCAN_BLOCKS, 256, 0, stream>>>(d, partials, rowptr, cursor);

    // fused t1 | fill (interleaved block types; 2-phase 16.6KB LDS, R10-proven)
    t1fill_k<<<2 * (N_NODES / 16), 256, 0, stream>>>(h, wb, t1_b, gw, xb0, gd0, gs0,
                                                     src, dst, yn, cursor, csr);

    int wave_blocks = (N_NODES * 64 + 255) / 256;   // one wave per node

    // layer 0: gather xb0, residual xb0 -> xb1, fused layer-1 gate dots
    agg_k<<<wave_blocks, 256, 0, stream>>>(xb0, xb0, rowptr, csr, d, gd0, gs0, gb, 0,
                                           yw, nw, gw + 256, gd1, gs1, xb1);
    // layer 1: gather xb1, residual xb0 (raw is FIXED across layers) -> xb2
    agg_k<<<wave_blocks, 256, 0, stream>>>(xb1, xb0, rowptr, csr, d, gd1, gs1, gb, 1,
                                           yw, nw, (const float*)nullptr,
                                           (float*)nullptr, (float*)nullptr, xb2);

    // t2 + log_softmax (bf16 x, R4-proven)
    out_k<<<(N_NODES + 63) / 64, 256, 0, stream>>>(xb2, t2_w, t2_b, outp);
}

// Round 13
// 317.665 us; speedup vs baseline: 1.0591x; 1.0193x over previous
//
#include <hip/hip_runtime.h>
#include <math.h>

#define N_NODES 50000
#define N_EDGES 800000
#define IN_DIM  512
#define HID     128
#define OUT_DIM 64
#define EPS     0.3f

#define SCAN_BLOCKS 49   // ceil(50000 / 1024)
#define LDS_ROW_H 260    // 256 + 4 dword pad (half-K staging row)
#define FILL_BLOCKS 400  // grid-strided fill: 102400 threads x ~8 edges

typedef __attribute__((ext_vector_type(8))) short bf16x8;
typedef __attribute__((ext_vector_type(8))) __bf16 bf16v8;
typedef __attribute__((ext_vector_type(4))) float f32x4;

__device__ __forceinline__ float fast_tanh(float x) {
    // tanh(x) = 1 - 2/(exp(2x)+1); saturates correctly at +/-inf
    return 1.0f - 2.0f / (__expf(2.0f * x) + 1.0f);
}

// f32 -> bf16 via native cast: compiler emits v_cvt_pk_bf16_f32 (RNE).
__device__ __forceinline__ unsigned short f2bfu(float f) {
    return __builtin_bit_cast(unsigned short, (__bf16)f);
}
__device__ __forceinline__ unsigned pk2(float lo, float hi) {
    return (unsigned)f2bfu(lo) | ((unsigned)f2bfu(hi) << 16);
}
__device__ __forceinline__ float bf_lo(unsigned u) { return __uint_as_float(u << 16); }
__device__ __forceinline__ float bf_hi(unsigned u) { return __uint_as_float(u & 0xffff0000u); }

// degree recovered from input d = rsqrt(deg+1): deg = round(1/d^2) - 1.
__device__ __forceinline__ int deg_of(float dv) {
    return (int)(1.0f / (dv * dv) + 0.5f) - 1;
}

// ---------------- hw: [blk 0..48] degree partials | [49..80] W pack ----------
// R9-proven two-dispatch prep. R8 lesson: NEVER one-block serial scans (58us).
// R10 lesson: merged self-sufficient scan costs more than the gap it saves.
// R11 lesson: nt stores on scattered small writes regressed -> plain stores.

__global__ void hw_k(const float* __restrict__ d, int* __restrict__ partials,
                     const float* __restrict__ w, unsigned short* __restrict__ wb) {
    int bid = blockIdx.x, tid = threadIdx.x;

    if (bid < SCAN_BLOCKS) {
        int base = bid * 1024 + tid * 4;
        int s = 0;
#pragma unroll
        for (int j = 0; j < 4; j++) if (base + j < N_NODES) s += deg_of(d[base + j]);
#pragma unroll
        for (int off = 32; off; off >>= 1) s += __shfl_down(s, off);
        __shared__ int ws[4];
        int lane = tid & 63, wv = tid >> 6;
        if (lane == 0) ws[wv] = s;
        __syncthreads();
        if (tid == 0) partials[bid] = ws[0] + ws[1] + ws[2] + ws[3];
        return;
    }

    // ---- W pack: MFMA B-fragment order (blocks 49..80, 8192 jobs) ----
    int t = (bid - SCAN_BLOCKS) * 256 + tid;
    int lane = t & 63;
    int ct   = (t >> 6) & 7;
    int ks   = t >> 9;
    int row  = ct * 16 + (lane & 15);
    int kb   = ks * 32 + (lane >> 4) * 8;
    const float* p = &w[(size_t)row * IN_DIM + kb];
    float4 v0 = *(const float4*)p, v1 = *(const float4*)(p + 4);
    uint4 pk;
    pk.x = pk2(v0.x, v0.y);
    pk.y = pk2(v0.z, v0.w);
    pk.z = pk2(v1.x, v1.y);
    pk.w = pk2(v1.z, v1.w);
    *(uint4*)&wb[(size_t)t * 8] = pk;
}

// ---------------- scanw: block scan + in-wave block offset -> rowptr/cursor --

__global__ void scanw_k(const float* __restrict__ d, const int* __restrict__ partials,
                        int* __restrict__ rowptr, int* __restrict__ cursor) {
    int tid = threadIdx.x;
    int base = blockIdx.x * 1024 + tid * 4;
    int v[4]; int s = 0;
#pragma unroll
    for (int j = 0; j < 4; j++) {
        v[j] = (base + j < N_NODES) ? deg_of(d[base + j]) : 0;
        s += v[j];
    }
    int lane = tid & 63, wv = tid >> 6;
    int sc = s;
#pragma unroll
    for (int off = 1; off < 64; off <<= 1) {
        int t = __shfl_up(sc, off);
        if (lane >= off) sc += t;
    }
    __shared__ int wtot[4];
    __shared__ int bofs_s;
    if (lane == 63) wtot[wv] = sc;
    // wave 0: block offset = sum of partials[0..blockIdx-1] (blockIdx <= 48 < 64)
    if (tid < 64) {
        int p = (tid < blockIdx.x) ? partials[tid] : 0;
#pragma unroll
        for (int off = 32; off; off >>= 1) p += __shfl_down(p, off);
        if (tid == 0) bofs_s = p;
    }
    __syncthreads();
    int wof = 0;
    for (int w = 0; w < wv; w++) wof += wtot[w];
    int excl = bofs_s + wof + (sc - s);
#pragma unroll
    for (int j = 0; j < 4; j++) {
        if (base + j < N_NODES) { rowptr[base + j] = excl; cursor[base + j] = excl; }
        excl += v[j];
    }
    if (blockIdx.x == SCAN_BLOCKS - 1 && tid == 0)
        rowptr[N_NODES] = bofs_s + wtot[0] + wtot[1] + wtot[2] + wtot[3];
}

// ---------------- fused t1 (2-phase MFMA tile) | fill (grid-strided scatter) --
// R13: fill is atomic-rate bound (~14.3G/s, invariant R3/R4/R9/R10) and needs
// only ~7K outstanding atomics to saturate. The old 1:1 block interleave gave
// fill HALF of all wave slots -- thousands of waves stalled in the atomic
// queue starved t1 (84us = 56+28 SUM). v3: fill = 400 grid-strided blocks
// launched FIRST (102400 threads, ~8 edges each, 14x the needed outstanding
// atomics); t1's 3125 blocks fill the remaining ~90% of slots and overlap
// inside fill's 56us atomic drain.

__launch_bounds__(256)
__global__ void t1fill_k(const float* __restrict__ h, const unsigned short* __restrict__ wb,
                         const float* __restrict__ bias, const float* __restrict__ gw0,
                         unsigned short* __restrict__ xb0,
                         float* __restrict__ gd0, float* __restrict__ gs0,
                         const int* __restrict__ src, const int* __restrict__ dst,
                         const int* __restrict__ yn, int* __restrict__ cursor,
                         int* __restrict__ csr) {
    __shared__ float At[16 * LDS_ROW_H];    // 16.6 KB half-K staging buffer
    __shared__ float red[4][4][4][2];       // gate partials [wave][quad][r][pd|ps]

    if (blockIdx.x < FILL_BLOCKS) {
        // ---- fill: grid-stride over edges; independent iterations pipeline ----
        for (int e = blockIdx.x * 256 + threadIdx.x; e < N_EDGES;
             e += FILL_BLOCKS * 256) {
            int dv = dst[e];
            int pos = atomicAdd(&cursor[dv], 1);
            csr[pos] = src[e] | (yn[e] << 31);   // src < 2^17, yn in sign bit
        }
        return;
    }

    // ---- t1 half (R10-proven 2-phase staging) ----
    int tid  = threadIdx.x;
    int lane = tid & 63;
    int wv   = tid >> 6;
    int l15  = lane & 15;
    int quad = lane >> 4;
    int rowb = (blockIdx.x - FILL_BLOCKS) * 16;   // 50000 = 3125*16, no tail

    int ct0 = wv * 2;
    const unsigned short* bp = &wb[(size_t)lane * 8];
    const float* arp = &At[l15 * LDS_ROW_H + quad * 8];
    f32x4 acc[2];
    acc[0] = (f32x4){0.f, 0.f, 0.f, 0.f};
    acc[1] = (f32x4){0.f, 0.f, 0.f, 0.f};

#pragma unroll
    for (int ph = 0; ph < 2; ++ph) {
        // stage: 16 chunks of 1KB (chunk = row, half ph), 4 per wave.
#pragma unroll
        for (int i = 0; i < 4; ++i) {
            int row = wv * 4 + i;
            const float* gsrc = &h[(size_t)(rowb + row) * IN_DIM + ph * 256 + lane * 4];
            float* ldst = &At[row * LDS_ROW_H];
            __builtin_amdgcn_global_load_lds(
                (const __attribute__((address_space(1))) unsigned int*)gsrc,
                (__attribute__((address_space(3))) unsigned int*)ldst, 16, 0, 0);
        }
        __syncthreads();    // drains vmcnt -> staged data visible

#pragma unroll 4
        for (int ks = 0; ks < 8; ++ks) {
            int ks_g = ph * 8 + ks;
            float4 a0 = *(const float4*)(arp + ks * 32);
            float4 a1 = *(const float4*)(arp + ks * 32 + 4);
            bf16v8 av;
            av[0] = (__bf16)a0.x; av[1] = (__bf16)a0.y;
            av[2] = (__bf16)a0.z; av[3] = (__bf16)a0.w;
            av[4] = (__bf16)a1.x; av[5] = (__bf16)a1.y;
            av[6] = (__bf16)a1.z; av[7] = (__bf16)a1.w;
            bf16x8 af = __builtin_bit_cast(bf16x8, av);
            bf16x8 b0 = *(const bf16x8*)(bp + (size_t)(ks_g * 8 + ct0) * 512);
            bf16x8 b1 = *(const bf16x8*)(bp + (size_t)(ks_g * 8 + ct0 + 1) * 512);
            acc[0] = __builtin_amdgcn_mfma_f32_16x16x32_bf16(af, b0, acc[0], 0, 0, 0);
            acc[1] = __builtin_amdgcn_mfma_f32_16x16x32_bf16(af, b1, acc[1], 0, 0, 0);
        }
        __syncthreads();    // all waves done reading before next-phase overwrite
    }

    // epilogue: bias+relu, store bf16, gate partials for this wave's 32 cols
    float pd[4] = {0.f, 0.f, 0.f, 0.f}, ps[4] = {0.f, 0.f, 0.f, 0.f};
#pragma unroll
    for (int ct = 0; ct < 2; ++ct) {
        int o = (ct0 + ct) * 16 + l15;
        float b = bias[o];
        float wd = gw0[o], wsv = gw0[128 + o];
#pragma unroll
        for (int r = 0; r < 4; ++r) {
            float v = acc[ct][r] + b;
            v = v > 0.f ? v : 0.f;
            int node = rowb + quad * 4 + r;
            xb0[(size_t)node * HID + o] = f2bfu(v);
            pd[r] += v * wd; ps[r] += v * wsv;
        }
    }
    // reduce over the 16 lanes of l15
#pragma unroll
    for (int m = 1; m < 16; m <<= 1) {
#pragma unroll
        for (int r = 0; r < 4; ++r) {
            pd[r] += __shfl_xor(pd[r], m);
            ps[r] += __shfl_xor(ps[r], m);
        }
    }
    if (l15 == 0) {
#pragma unroll
        for (int r = 0; r < 4; ++r) {
            red[wv][quad][r][0] = pd[r];
            red[wv][quad][r][1] = ps[r];
        }
    }
    __syncthreads();
    // cross-wave sum: 16 rows handled by lanes 0..15 of wave 0
    if (wv == 0 && lane < 16) {
        int q = lane >> 2, r = lane & 3;
        float sd = red[0][q][r][0] + red[1][q][r][0] + red[2][q][r][0] + red[3][q][r][0];
        float ss = red[0][q][r][1] + red[1][q][r][1] + red[2][q][r][1] + red[3][q][r][1];
        gd0[rowb + lane] = sd;
        gs0[rowb + lane] = ss;
    }
}

// ---------------- aggregation (R4/R9-proven v5, verbatim) + fused next gate ---
// One wave per dst node. Batch phase: lane e computes coef for edge e0+lane.
// Gather phase: 4 edges/trip, 16 lanes/edge, coef/src broadcast via __shfl,
// depth-2 software pipeline. R2/R3: keep coef inline. R6: separate gd/gs/d
// tables. R7: no t2-GEMV fusion (spill). R11: plain stores.

__global__ void agg_k(const unsigned short* __restrict__ xb,
                      const unsigned short* __restrict__ rb,
                      const int* __restrict__ rowptr, const int* __restrict__ csr,
                      const float* __restrict__ d,
                      const float* __restrict__ gd, const float* __restrict__ gs,
                      const float* __restrict__ gb, int layer,
                      const float* __restrict__ yw, const float* __restrict__ nw,
                      const float* __restrict__ gw_next,
                      float* __restrict__ gd_out, float* __restrict__ gs_out,
                      unsigned short* __restrict__ xb_out) {
    int t = blockIdx.x * blockDim.x + threadIdx.x;
    int nid = t >> 6, lane = t & 63;
    if (nid >= N_NODES) return;
    int l15 = lane & 15, eg = lane >> 4;
    float acc[8];
#pragma unroll
    for (int j = 0; j < 8; j++) acc[j] = 0.f;
    if (lane < 16) {
        uint4 rv = *(const uint4*)&rb[(size_t)nid * HID + l15 * 8];
        acc[0] = EPS * bf_lo(rv.x); acc[1] = EPS * bf_hi(rv.x);
        acc[2] = EPS * bf_lo(rv.y); acc[3] = EPS * bf_hi(rv.y);
        acc[4] = EPS * bf_lo(rv.z); acc[5] = EPS * bf_hi(rv.z);
        acc[6] = EPS * bf_lo(rv.w); acc[7] = EPS * bf_hi(rv.w);
    }
    float gdn = gd[nid] + gb[layer];
    float dn  = d[nid];
    float ty  = fast_tanh(yw[0]);
    float tno = fast_tanh(nw[0]);
    int e0 = rowptr[nid], e1 = rowptr[nid + 1];
    for (int b0 = e0; b0 < e1; b0 += 64) {
        int e = b0 + lane;
        float cf = 0.f; int sidx = 0;
        if (e < e1) {
            int p = csr[e];
            int s = p & 0x7fffffff;
            float ynt = (p < 0) ? ty : tno;
            cf = (fast_tanh(gdn + gs[s]) + ynt) * 0.5f * dn * d[s];
            sidx = s;
        }
        int trips = e1 - b0; if (trips > 64) trips = 64;
        // prime trip 0
        float cfA = __shfl(cf, eg);
        int   sA  = __shfl(sidx, eg);
        uint4 vA  = *(const uint4*)&xb[(size_t)sA * HID + l15 * 8];
        for (int t4 = 0; t4 < trips; t4 += 4) {
            // prefetch trip t4+4 (wave-uniform branch; nx <= 63 always)
            float cfB = 0.f; uint4 vB = make_uint4(0, 0, 0, 0);
            if (t4 + 4 < trips) {
                int nx = t4 + 4 + eg;
                cfB = __shfl(cf, nx);
                int sB = __shfl(sidx, nx);
                vB = *(const uint4*)&xb[(size_t)sB * HID + l15 * 8];
            }
            acc[0] += cfA * bf_lo(vA.x); acc[1] += cfA * bf_hi(vA.x);
            acc[2] += cfA * bf_lo(vA.y); acc[3] += cfA * bf_hi(vA.y);
            acc[4] += cfA * bf_lo(vA.z); acc[5] += cfA * bf_hi(vA.z);
            acc[6] += cfA * bf_lo(vA.w); acc[7] += cfA * bf_hi(vA.w);
            cfA = cfB; vA = vB;
        }
    }
    // fold the 4 edge-groups: after this ALL lanes hold the full row chunk for l15
#pragma unroll
    for (int j = 0; j < 8; j++) acc[j] += __shfl_xor(acc[j], 32);
#pragma unroll
    for (int j = 0; j < 8; j++) acc[j] += __shfl_xor(acc[j], 16);
    if (lane < 16) {
        uint4 pk;
        pk.x = pk2(acc[0], acc[1]);
        pk.y = pk2(acc[2], acc[3]);
        pk.z = pk2(acc[4], acc[5]);
        pk.w = pk2(acc[6], acc[7]);
        *(uint4*)&xb_out[(size_t)nid * HID + l15 * 8] = pk;
    }
    // fused next-layer gate dots (layer 0 only)
    if (gw_next) {
        float pd = 0.f, psv = 0.f;
#pragma unroll
        for (int j = 0; j < 8; j++) {
            int o = l15 * 8 + j;
            pd  += acc[j] * gw_next[o];
            psv += acc[j] * gw_next[128 + o];
        }
#pragma unroll
        for (int m = 1; m < 16; m <<= 1) {
            pd  += __shfl_xor(pd, m);
            psv += __shfl_xor(psv, m);
        }
        if (lane == 0) { gd_out[nid] = pd; gs_out[nid] = psv; }
    }
}

// ---------------- t2 + log_softmax: 64-node tile per block (bf16 x) ----------------

__launch_bounds__(256)
__global__ void out_k(const unsigned short* __restrict__ xb, const float* __restrict__ w,
                      const float* __restrict__ bias, float* __restrict__ out) {
    __shared__ float As[64][132];   // 64 nodes x 128 k
    __shared__ float Bs[64][132];   // 64 outs  x 128 k
    int tid = threadIdx.x;
    int n0  = blockIdx.x * 64;
#pragma unroll
    for (int j = 0; j < 4; j++) {
        int c8 = tid + j * 256;          // 1024 chunks of 8 bf16
        int r = c8 >> 4, c = (c8 & 15) * 8;
        int gr = n0 + r;
        uint4 v = make_uint4(0, 0, 0, 0);
        if (gr < N_NODES) v = *(const uint4*)&xb[(size_t)gr * HID + c];
        *(float4*)&As[r][c]     = make_float4(bf_lo(v.x), bf_hi(v.x), bf_lo(v.y), bf_hi(v.y));
        *(float4*)&As[r][c + 4] = make_float4(bf_lo(v.z), bf_hi(v.z), bf_lo(v.w), bf_hi(v.w));
    }
#pragma unroll
    for (int j = 0; j < 8; j++) {
        int f4 = tid + j * 256;
        int r = f4 >> 5, c = (f4 & 31) * 4;
        *(float4*)&Bs[r][c] = *(const float4*)&w[r * HID + c];
    }
    __syncthreads();
    int tn = tid >> 4, to = tid & 15;
    float acc[4][4];
#pragma unroll
    for (int i = 0; i < 4; i++)
#pragma unroll
        for (int j = 0; j < 4; j++) acc[i][j] = 0.0f;
    // unroll capped at 2: full unroll was the VGPR=256 spill (R1)
#pragma unroll 2
    for (int k = 0; k < HID; k += 4) {
        float4 av[4], bv[4];
#pragma unroll
        for (int i = 0; i < 4; i++) av[i] = *(const float4*)&As[tn + 16 * i][k];
#pragma unroll
        for (int j = 0; j < 4; j++) bv[j] = *(const float4*)&Bs[to + 16 * j][k];
#pragma unroll
        for (int i = 0; i < 4; i++)
#pragma unroll
            for (int j = 0; j < 4; j++) {
                acc[i][j] += av[i].x * bv[j].x;
                acc[i][j] += av[i].y * bv[j].y;
                acc[i][j] += av[i].z * bv[j].z;
                acc[i][j] += av[i].w * bv[j].w;
            }
    }
    float bj[4];
#pragma unroll
    for (int j = 0; j < 4; j++) bj[j] = bias[to + 16 * j];
#pragma unroll
    for (int i = 0; i < 4; i++) {
        float v[4];
        float m = -1e30f;
#pragma unroll
        for (int j = 0; j < 4; j++) { v[j] = acc[i][j] + bj[j]; m = fmaxf(m, v[j]); }
#pragma unroll
        for (int s = 1; s < 16; s <<= 1) m = fmaxf(m, __shfl_xor(m, s));
        float sum = 0.f;
#pragma unroll
        for (int j = 0; j < 4; j++) sum += __expf(v[j] - m);
#pragma unroll
        for (int s = 1; s < 16; s <<= 1) sum += __shfl_xor(sum, s);
        float lse = m + __logf(sum);
        int r = n0 + tn + 16 * i;
        if (r < N_NODES) {
#pragma unroll
            for (int j = 0; j < 4; j++) out[r * OUT_DIM + to + 16 * j] = v[j] - lse;
        }
    }
}

// ---------------- launcher ----------------

extern "C" void kernel_launch(void* const* d_in, const int* in_sizes, int n_in,
                              void* d_out, int out_size, void* d_ws, size_t ws_size,
                              hipStream_t stream) {
    const float* h    = (const float*)d_in[0];
    const float* d    = (const float*)d_in[1];
    const float* t1_w = (const float*)d_in[2];
    const float* t1_b = (const float*)d_in[3];
    const float* gw   = (const float*)d_in[4];   // [2][256]
    const float* gb   = (const float*)d_in[5];   // [2]
    const float* t2_w = (const float*)d_in[6];   // [64][128]
    const float* t2_b = (const float*)d_in[7];
    const float* yw   = (const float*)d_in[8];
    const float* nw   = (const float*)d_in[9];
    const int* src    = (const int*)d_in[10];
    const int* dst    = (const int*)d_in[11];
    const int* yn     = (const int*)d_in[12];
    float* outp = (float*)d_out;

    char* ws = (char*)d_ws;
    size_t off = 0;
    auto alloc = [&](size_t bytes) {
        void* p = ws + off;
        off = (off + bytes + 255) & ~(size_t)255;
        return p;
    };
    unsigned short* xb0 = (unsigned short*)alloc((size_t)N_NODES * HID * 2);
    unsigned short* xb1 = (unsigned short*)alloc((size_t)N_NODES * HID * 2);
    unsigned short* xb2 = (unsigned short*)alloc((size_t)N_NODES * HID * 2);
    unsigned short* wb  = (unsigned short*)alloc((size_t)8192 * 8 * 2);
    float* gd0    = (float*)alloc((size_t)N_NODES * 4);
    float* gs0    = (float*)alloc((size_t)N_NODES * 4);
    float* gd1    = (float*)alloc((size_t)N_NODES * 4);
    float* gs1    = (float*)alloc((size_t)N_NODES * 4);
    int*   rowptr = (int*)alloc((size_t)(N_NODES + 1) * 4);
    int*   cursor = (int*)alloc((size_t)N_NODES * 4);
    int*   csr    = (int*)alloc((size_t)N_EDGES * 4);
    int*   partials = (int*)alloc(64 * 4);
    (void)ws_size; (void)n_in; (void)in_sizes; (void)out_size;

    // degree partials + W pack (independent, coalesced, parallel; R9-proven)
    hw_k<<<SCAN_BLOCKS + 32, 256, 0, stream>>>(d, partials, t1_w, wb);
    // rowptr/cursor scan (each block derives its own offset from partials)
    scanw_k<<<SCAN_BLOCKS, 256, 0, stream>>>(d, partials, rowptr, cursor);

    // fused t1 | fill (fill = 400 grid-strided blocks launched first;
    // t1 = 3125 tile blocks overlap inside fill's atomic drain)
    t1fill_k<<<FILL_BLOCKS + N_NODES / 16, 256, 0, stream>>>(h, wb, t1_b, gw,
                                                             xb0, gd0, gs0,
                                                             src, dst, yn, cursor, csr);

    int wave_blocks = (N_NODES * 64 + 255) / 256;   // one wave per node

    // layer 0: gather xb0, residual xb0 -> xb1, fused layer-1 gate dots
    agg_k<<<wave_blocks, 256, 0, stream>>>(xb0, xb0, rowptr, csr, d, gd0, gs0, gb, 0,
                                           yw, nw, gw + 256, gd1, gs1, xb1);
    // layer 1: gather xb1, residual xb0 (raw is FIXED across layers) -> xb2
    agg_k<<<wave_blocks, 256, 0, stream>>>(xb1, xb0, rowptr, csr, d, gd1, gs1, gb, 1,
                                           yw, nw, (const float*)nullptr,
                                           (float*)nullptr, (float*)nullptr, xb2);

    // t2 + log_softmax (bf16 x, R4-proven)
    out_k<<<(N_NODES + 63) / 64, 256, 0, stream>>>(xb2, t2_w, t2_b, outp);
}

// Round 14
// 315.348 us; speedup vs baseline: 1.0668x; 1.0073x over previous
//
#include <hip/hip_runtime.h>
#include <math.h>

#define N_NODES 50000
#define N_EDGES 800000
#define IN_DIM  512
#define HID     128
#define OUT_DIM 64
#define EPS     0.3f

#define SCAN_BLOCKS 49   // ceil(50000 / 1024)
#define LDS_ROW_H 260    // 256 + 4 dword pad (half-K staging row)
#define FILL_BLOCKS 160  // grid-strided fill: 40960 threads x ~20 edges (R14 sweep)

typedef __attribute__((ext_vector_type(8))) short bf16x8;
typedef __attribute__((ext_vector_type(8))) __bf16 bf16v8;
typedef __attribute__((ext_vector_type(4))) float f32x4;

__device__ __forceinline__ float fast_tanh(float x) {
    // tanh(x) = 1 - 2/(exp(2x)+1); saturates correctly at +/-inf
    return 1.0f - 2.0f / (__expf(2.0f * x) + 1.0f);
}

// f32 -> bf16 via native cast: compiler emits v_cvt_pk_bf16_f32 (RNE).
__device__ __forceinline__ unsigned short f2bfu(float f) {
    return __builtin_bit_cast(unsigned short, (__bf16)f);
}
__device__ __forceinline__ unsigned pk2(float lo, float hi) {
    return (unsigned)f2bfu(lo) | ((unsigned)f2bfu(hi) << 16);
}
__device__ __forceinline__ float bf_lo(unsigned u) { return __uint_as_float(u << 16); }
__device__ __forceinline__ float bf_hi(unsigned u) { return __uint_as_float(u & 0xffff0000u); }

// degree recovered from input d = rsqrt(deg+1): deg = round(1/d^2) - 1.
__device__ __forceinline__ int deg_of(float dv) {
    return (int)(1.0f / (dv * dv) + 0.5f) - 1;
}

// ---------------- hw: [blk 0..48] degree partials | [49..80] W pack ----------
// R9-proven two-dispatch prep. R8 lesson: NEVER one-block serial scans (58us).
// R10 lesson: merged self-sufficient scan costs more than the gap it saves.
// R11 lesson: nt stores on scattered small writes regressed -> plain stores.

__global__ void hw_k(const float* __restrict__ d, int* __restrict__ partials,
                     const float* __restrict__ w, unsigned short* __restrict__ wb) {
    int bid = blockIdx.x, tid = threadIdx.x;

    if (bid < SCAN_BLOCKS) {
        int base = bid * 1024 + tid * 4;
        int s = 0;
#pragma unroll
        for (int j = 0; j < 4; j++) if (base + j < N_NODES) s += deg_of(d[base + j]);
#pragma unroll
        for (int off = 32; off; off >>= 1) s += __shfl_down(s, off);
        __shared__ int ws[4];
        int lane = tid & 63, wv = tid >> 6;
        if (lane == 0) ws[wv] = s;
        __syncthreads();
        if (tid == 0) partials[bid] = ws[0] + ws[1] + ws[2] + ws[3];
        return;
    }

    // ---- W pack: MFMA B-fragment order (blocks 49..80, 8192 jobs) ----
    int t = (bid - SCAN_BLOCKS) * 256 + tid;
    int lane = t & 63;
    int ct   = (t >> 6) & 7;
    int ks   = t >> 9;
    int row  = ct * 16 + (lane & 15);
    int kb   = ks * 32 + (lane >> 4) * 8;
    const float* p = &w[(size_t)row * IN_DIM + kb];
    float4 v0 = *(const float4*)p, v1 = *(const float4*)(p + 4);
    uint4 pk;
    pk.x = pk2(v0.x, v0.y);
    pk.y = pk2(v0.z, v0.w);
    pk.z = pk2(v1.x, v1.y);
    pk.w = pk2(v1.z, v1.w);
    *(uint4*)&wb[(size_t)t * 8] = pk;
}

// ---------------- scanw: block scan + in-wave block offset -> rowptr/cursor --

__global__ void scanw_k(const float* __restrict__ d, const int* __restrict__ partials,
                        int* __restrict__ rowptr, int* __restrict__ cursor) {
    int tid = threadIdx.x;
    int base = blockIdx.x * 1024 + tid * 4;
    int v[4]; int s = 0;
#pragma unroll
    for (int j = 0; j < 4; j++) {
        v[j] = (base + j < N_NODES) ? deg_of(d[base + j]) : 0;
        s += v[j];
    }
    int lane = tid & 63, wv = tid >> 6;
    int sc = s;
#pragma unroll
    for (int off = 1; off < 64; off <<= 1) {
        int t = __shfl_up(sc, off);
        if (lane >= off) sc += t;
    }
    __shared__ int wtot[4];
    __shared__ int bofs_s;
    if (lane == 63) wtot[wv] = sc;
    // wave 0: block offset = sum of partials[0..blockIdx-1] (blockIdx <= 48 < 64)
    if (tid < 64) {
        int p = (tid < blockIdx.x) ? partials[tid] : 0;
#pragma unroll
        for (int off = 32; off; off >>= 1) p += __shfl_down(p, off);
        if (tid == 0) bofs_s = p;
    }
    __syncthreads();
    int wof = 0;
    for (int w = 0; w < wv; w++) wof += wtot[w];
    int excl = bofs_s + wof + (sc - s);
#pragma unroll
    for (int j = 0; j < 4; j++) {
        if (base + j < N_NODES) { rowptr[base + j] = excl; cursor[base + j] = excl; }
        excl += v[j];
    }
    if (blockIdx.x == SCAN_BLOCKS - 1 && tid == 0)
        rowptr[N_NODES] = bofs_s + wtot[0] + wtot[1] + wtot[2] + wtot[3];
}

// ---------------- fused t1 (2-phase MFMA tile) | fill (grid-strided scatter) --
// R13 post-mortem: FILL_BLOCKS=400 gave t1fill 84->78us, occupancy 28->36%.
// Ideal overlap = ~58us (max of fill's 56us atomic drain and t1's ~35us at
// reduced capacity); the ~20us excess is either residual slot displacement
// (fill waves ~20% of slots) or fabric interference. R14 sweep: 160 blocks
// (~8% of slots; 40960 threads, 6x the outstanding atomics needed; 20
// edges/thread serial chain ~20us << 56us rate window -> fill time safe).

__launch_bounds__(256)
__global__ void t1fill_k(const float* __restrict__ h, const unsigned short* __restrict__ wb,
                         const float* __restrict__ bias, const float* __restrict__ gw0,
                         unsigned short* __restrict__ xb0,
                         float* __restrict__ gd0, float* __restrict__ gs0,
                         const int* __restrict__ src, const int* __restrict__ dst,
                         const int* __restrict__ yn, int* __restrict__ cursor,
                         int* __restrict__ csr) {
    __shared__ float At[16 * LDS_ROW_H];    // 16.6 KB half-K staging buffer
    __shared__ float red[4][4][4][2];       // gate partials [wave][quad][r][pd|ps]

    if (blockIdx.x < FILL_BLOCKS) {
        // ---- fill: grid-stride over edges; independent iterations pipeline ----
        for (int e = blockIdx.x * 256 + threadIdx.x; e < N_EDGES;
             e += FILL_BLOCKS * 256) {
            int dv = dst[e];
            int pos = atomicAdd(&cursor[dv], 1);
            csr[pos] = src[e] | (yn[e] << 31);   // src < 2^17, yn in sign bit
        }
        return;
    }

    // ---- t1 half (R10-proven 2-phase staging) ----
    int tid  = threadIdx.x;
    int lane = tid & 63;
    int wv   = tid >> 6;
    int l15  = lane & 15;
    int quad = lane >> 4;
    int rowb = (blockIdx.x - FILL_BLOCKS) * 16;   // 50000 = 3125*16, no tail

    int ct0 = wv * 2;
    const unsigned short* bp = &wb[(size_t)lane * 8];
    const float* arp = &At[l15 * LDS_ROW_H + quad * 8];
    f32x4 acc[2];
    acc[0] = (f32x4){0.f, 0.f, 0.f, 0.f};
    acc[1] = (f32x4){0.f, 0.f, 0.f, 0.f};

#pragma unroll
    for (int ph = 0; ph < 2; ++ph) {
        // stage: 16 chunks of 1KB (chunk = row, half ph), 4 per wave.
#pragma unroll
        for (int i = 0; i < 4; ++i) {
            int row = wv * 4 + i;
            const float* gsrc = &h[(size_t)(rowb + row) * IN_DIM + ph * 256 + lane * 4];
            float* ldst = &At[row * LDS_ROW_H];
            __builtin_amdgcn_global_load_lds(
                (const __attribute__((address_space(1))) unsigned int*)gsrc,
                (__attribute__((address_space(3))) unsigned int*)ldst, 16, 0, 0);
        }
        __syncthreads();    // drains vmcnt -> staged data visible

#pragma unroll 4
        for (int ks = 0; ks < 8; ++ks) {
            int ks_g = ph * 8 + ks;
            float4 a0 = *(const float4*)(arp + ks * 32);
            float4 a1 = *(const float4*)(arp + ks * 32 + 4);
            bf16v8 av;
            av[0] = (__bf16)a0.x; av[1] = (__bf16)a0.y;
            av[2] = (__bf16)a0.z; av[3] = (__bf16)a0.w;
            av[4] = (__bf16)a1.x; av[5] = (__bf16)a1.y;
            av[6] = (__bf16)a1.z; av[7] = (__bf16)a1.w;
            bf16x8 af = __builtin_bit_cast(bf16x8, av);
            bf16x8 b0 = *(const bf16x8*)(bp + (size_t)(ks_g * 8 + ct0) * 512);
            bf16x8 b1 = *(const bf16x8*)(bp + (size_t)(ks_g * 8 + ct0 + 1) * 512);
            acc[0] = __builtin_amdgcn_mfma_f32_16x16x32_bf16(af, b0, acc[0], 0, 0, 0);
            acc[1] = __builtin_amdgcn_mfma_f32_16x16x32_bf16(af, b1, acc[1], 0, 0, 0);
        }
        __syncthreads();    // all waves done reading before next-phase overwrite
    }

    // epilogue: bias+relu, store bf16, gate partials for this wave's 32 cols
    float pd[4] = {0.f, 0.f, 0.f, 0.f}, ps[4] = {0.f, 0.f, 0.f, 0.f};
#pragma unroll
    for (int ct = 0; ct < 2; ++ct) {
        int o = (ct0 + ct) * 16 + l15;
        float b = bias[o];
        float wd = gw0[o], wsv = gw0[128 + o];
#pragma unroll
        for (int r = 0; r < 4; ++r) {
            float v = acc[ct][r] + b;
            v = v > 0.f ? v : 0.f;
            int node = rowb + quad * 4 + r;
            xb0[(size_t)node * HID + o] = f2bfu(v);
            pd[r] += v * wd; ps[r] += v * wsv;
        }
    }
    // reduce over the 16 lanes of l15
#pragma unroll
    for (int m = 1; m < 16; m <<= 1) {
#pragma unroll
        for (int r = 0; r < 4; ++r) {
            pd[r] += __shfl_xor(pd[r], m);
            ps[r] += __shfl_xor(ps[r], m);
        }
    }
    if (l15 == 0) {
#pragma unroll
        for (int r = 0; r < 4; ++r) {
            red[wv][quad][r][0] = pd[r];
            red[wv][quad][r][1] = ps[r];
        }
    }
    __syncthreads();
    // cross-wave sum: 16 rows handled by lanes 0..15 of wave 0
    if (wv == 0 && lane < 16) {
        int q = lane >> 2, r = lane & 3;
        float sd = red[0][q][r][0] + red[1][q][r][0] + red[2][q][r][0] + red[3][q][r][0];
        float ss = red[0][q][r][1] + red[1][q][r][1] + red[2][q][r][1] + red[3][q][r][1];
        gd0[rowb + lane] = sd;
        gs0[rowb + lane] = ss;
    }
}

// ---------------- aggregation (R4/R9-proven v5, verbatim) + fused next gate ---
// One wave per dst node. Batch phase: lane e computes coef for edge e0+lane.
// Gather phase: 4 edges/trip, 16 lanes/edge, coef/src broadcast via __shfl,
// depth-2 software pipeline. R2/R3: keep coef inline. R6: separate gd/gs/d
// tables. R7: no t2-GEMV fusion (spill). R11: plain stores.

__global__ void agg_k(const unsigned short* __restrict__ xb,
                      const unsigned short* __restrict__ rb,
                      const int* __restrict__ rowptr, const int* __restrict__ csr,
                      const float* __restrict__ d,
                      const float* __restrict__ gd, const float* __restrict__ gs,
                      const float* __restrict__ gb, int layer,
                      const float* __restrict__ yw, const float* __restrict__ nw,
                      const float* __restrict__ gw_next,
                      float* __restrict__ gd_out, float* __restrict__ gs_out,
                      unsigned short* __restrict__ xb_out) {
    int t = blockIdx.x * blockDim.x + threadIdx.x;
    int nid = t >> 6, lane = t & 63;
    if (nid >= N_NODES) return;
    int l15 = lane & 15, eg = lane >> 4;
    float acc[8];
#pragma unroll
    for (int j = 0; j < 8; j++) acc[j] = 0.f;
    if (lane < 16) {
        uint4 rv = *(const uint4*)&rb[(size_t)nid * HID + l15 * 8];
        acc[0] = EPS * bf_lo(rv.x); acc[1] = EPS * bf_hi(rv.x);
        acc[2] = EPS * bf_lo(rv.y); acc[3] = EPS * bf_hi(rv.y);
        acc[4] = EPS * bf_lo(rv.z); acc[5] = EPS * bf_hi(rv.z);
        acc[6] = EPS * bf_lo(rv.w); acc[7] = EPS * bf_hi(rv.w);
    }
    float gdn = gd[nid] + gb[layer];
    float dn  = d[nid];
    float ty  = fast_tanh(yw[0]);
    float tno = fast_tanh(nw[0]);
    int e0 = rowptr[nid], e1 = rowptr[nid + 1];
    for (int b0 = e0; b0 < e1; b0 += 64) {
        int e = b0 + lane;
        float cf = 0.f; int sidx = 0;
        if (e < e1) {
            int p = csr[e];
            int s = p & 0x7fffffff;
            float ynt = (p < 0) ? ty : tno;
            cf = (fast_tanh(gdn + gs[s]) + ynt) * 0.5f * dn * d[s];
            sidx = s;
        }
        int trips = e1 - b0; if (trips > 64) trips = 64;
        // prime trip 0
        float cfA = __shfl(cf, eg);
        int   sA  = __shfl(sidx, eg);
        uint4 vA  = *(const uint4*)&xb[(size_t)sA * HID + l15 * 8];
        for (int t4 = 0; t4 < trips; t4 += 4) {
            // prefetch trip t4+4 (wave-uniform branch; nx <= 63 always)
            float cfB = 0.f; uint4 vB = make_uint4(0, 0, 0, 0);
            if (t4 + 4 < trips) {
                int nx = t4 + 4 + eg;
                cfB = __shfl(cf, nx);
                int sB = __shfl(sidx, nx);
                vB = *(const uint4*)&xb[(size_t)sB * HID + l15 * 8];
            }
            acc[0] += cfA * bf_lo(vA.x); acc[1] += cfA * bf_hi(vA.x);
            acc[2] += cfA * bf_lo(vA.y); acc[3] += cfA * bf_hi(vA.y);
            acc[4] += cfA * bf_lo(vA.z); acc[5] += cfA * bf_hi(vA.z);
            acc[6] += cfA * bf_lo(vA.w); acc[7] += cfA * bf_hi(vA.w);
            cfA = cfB; vA = vB;
        }
    }
    // fold the 4 edge-groups: after this ALL lanes hold the full row chunk for l15
#pragma unroll
    for (int j = 0; j < 8; j++) acc[j] += __shfl_xor(acc[j], 32);
#pragma unroll
    for (int j = 0; j < 8; j++) acc[j] += __shfl_xor(acc[j], 16);
    if (lane < 16) {
        uint4 pk;
        pk.x = pk2(acc[0], acc[1]);
        pk.y = pk2(acc[2], acc[3]);
        pk.z = pk2(acc[4], acc[5]);
        pk.w = pk2(acc[6], acc[7]);
        *(uint4*)&xb_out[(size_t)nid * HID + l15 * 8] = pk;
    }
    // fused next-layer gate dots (layer 0 only)
    if (gw_next) {
        float pd = 0.f, psv = 0.f;
#pragma unroll
        for (int j = 0; j < 8; j++) {
            int o = l15 * 8 + j;
            pd  += acc[j] * gw_next[o];
            psv += acc[j] * gw_next[128 + o];
        }
#pragma unroll
        for (int m = 1; m < 16; m <<= 1) {
            pd  += __shfl_xor(pd, m);
            psv += __shfl_xor(psv, m);
        }
        if (lane == 0) { gd_out[nid] = pd; gs_out[nid] = psv; }
    }
}

// ---------------- t2 + log_softmax: 64-node tile per block (bf16 x) ----------------

__launch_bounds__(256)
__global__ void out_k(const unsigned short* __restrict__ xb, const float* __restrict__ w,
                      const float* __restrict__ bias, float* __restrict__ out) {
    __shared__ float As[64][132];   // 64 nodes x 128 k
    __shared__ float Bs[64][132];   // 64 outs  x 128 k
    int tid = threadIdx.x;
    int n0  = blockIdx.x * 64;
#pragma unroll
    for (int j = 0; j < 4; j++) {
        int c8 = tid + j * 256;          // 1024 chunks of 8 bf16
        int r = c8 >> 4, c = (c8 & 15) * 8;
        int gr = n0 + r;
        uint4 v = make_uint4(0, 0, 0, 0);
        if (gr < N_NODES) v = *(const uint4*)&xb[(size_t)gr * HID + c];
        *(float4*)&As[r][c]     = make_float4(bf_lo(v.x), bf_hi(v.x), bf_lo(v.y), bf_hi(v.y));
        *(float4*)&As[r][c + 4] = make_float4(bf_lo(v.z), bf_hi(v.z), bf_lo(v.w), bf_hi(v.w));
    }
#pragma unroll
    for (int j = 0; j < 8; j++) {
        int f4 = tid + j * 256;
        int r = f4 >> 5, c = (f4 & 31) * 4;
        *(float4*)&Bs[r][c] = *(const float4*)&w[r * HID + c];
    }
    __syncthreads();
    int tn = tid >> 4, to = tid & 15;
    float acc[4][4];
#pragma unroll
    for (int i = 0; i < 4; i++)
#pragma unroll
        for (int j = 0; j < 4; j++) acc[i][j] = 0.0f;
    // unroll capped at 2: full unroll was the VGPR=256 spill (R1)
#pragma unroll 2
    for (int k = 0; k < HID; k += 4) {
        float4 av[4], bv[4];
#pragma unroll
        for (int i = 0; i < 4; i++) av[i] = *(const float4*)&As[tn + 16 * i][k];
#pragma unroll
        for (int j = 0; j < 4; j++) bv[j] = *(const float4*)&Bs[to + 16 * j][k];
#pragma unroll
        for (int i = 0; i < 4; i++)
#pragma unroll
            for (int j = 0; j < 4; j++) {
                acc[i][j] += av[i].x * bv[j].x;
                acc[i][j] += av[i].y * bv[j].y;
                acc[i][j] += av[i].z * bv[j].z;
                acc[i][j] += av[i].w * bv[j].w;
            }
    }
    float bj[4];
#pragma unroll
    for (int j = 0; j < 4; j++) bj[j] = bias[to + 16 * j];
#pragma unroll
    for (int i = 0; i < 4; i++) {
        float v[4];
        float m = -1e30f;
#pragma unroll
        for (int j = 0; j < 4; j++) { v[j] = acc[i][j] + bj[j]; m = fmaxf(m, v[j]); }
#pragma unroll
        for (int s = 1; s < 16; s <<= 1) m = fmaxf(m, __shfl_xor(m, s));
        float sum = 0.f;
#pragma unroll
        for (int j = 0; j < 4; j++) sum += __expf(v[j] - m);
#pragma unroll
        for (int s = 1; s < 16; s <<= 1) sum += __shfl_xor(sum, s);
        float lse = m + __logf(sum);
        int r = n0 + tn + 16 * i;
        if (r < N_NODES) {
#pragma unroll
            for (int j = 0; j < 4; j++) out[r * OUT_DIM + to + 16 * j] = v[j] - lse;
        }
    }
}

// ---------------- launcher ----------------

extern "C" void kernel_launch(void* const* d_in, const int* in_sizes, int n_in,
                              void* d_out, int out_size, void* d_ws, size_t ws_size,
                              hipStream_t stream) {
    const float* h    = (const float*)d_in[0];
    const float* d    = (const float*)d_in[1];
    const float* t1_w = (const float*)d_in[2];
    const float* t1_b = (const float*)d_in[3];
    const float* gw   = (const float*)d_in[4];   // [2][256]
    const float* gb   = (const float*)d_in[5];   // [2]
    const float* t2_w = (const float*)d_in[6];   // [64][128]
    const float* t2_b = (const float*)d_in[7];
    const float* yw   = (const float*)d_in[8];
    const float* nw   = (const float*)d_in[9];
    const int* src    = (const int*)d_in[10];
    const int* dst    = (const int*)d_in[11];
    const int* yn     = (const int*)d_in[12];
    float* outp = (float*)d_out;

    char* ws = (char*)d_ws;
    size_t off = 0;
    auto alloc = [&](size_t bytes) {
        void* p = ws + off;
        off = (off + bytes + 255) & ~(size_t)255;
        return p;
    };
    unsigned short* xb0 = (unsigned short*)alloc((size_t)N_NODES * HID * 2);
    unsigned short* xb1 = (unsigned short*)alloc((size_t)N_NODES * HID * 2);
    unsigned short* xb2 = (unsigned short*)alloc((size_t)N_NODES * HID * 2);
    unsigned short* wb  = (unsigned short*)alloc((size_t)8192 * 8 * 2);
    float* gd0    = (float*)alloc((size_t)N_NODES * 4);
    float* gs0    = (float*)alloc((size_t)N_NODES * 4);
    float* gd1    = (float*)alloc((size_t)N_NODES * 4);
    float* gs1    = (float*)alloc((size_t)N_NODES * 4);
    int*   rowptr = (int*)alloc((size_t)(N_NODES + 1) * 4);
    int*   cursor = (int*)alloc((size_t)N_NODES * 4);
    int*   csr    = (int*)alloc((size_t)N_EDGES * 4);
    int*   partials = (int*)alloc(64 * 4);
    (void)ws_size; (void)n_in; (void)in_sizes; (void)out_size;

    // degree partials + W pack (independent, coalesced, parallel; R9-proven)
    hw_k<<<SCAN_BLOCKS + 32, 256, 0, stream>>>(d, partials, t1_w, wb);
    // rowptr/cursor scan (each block derives its own offset from partials)
    scanw_k<<<SCAN_BLOCKS, 256, 0, stream>>>(d, partials, rowptr, cursor);

    // fused t1 | fill (fill = 160 grid-strided blocks launched first;
    // t1 = 3125 tile blocks overlap inside fill's atomic drain)
    t1fill_k<<<FILL_BLOCKS + N_NODES / 16, 256, 0, stream>>>(h, wb, t1_b, gw,
                                                             xb0, gd0, gs0,
                                                             src, dst, yn, cursor, csr);

    int wave_blocks = (N_NODES * 64 + 255) / 256;   // one wave per node

    // layer 0: gather xb0, residual xb0 -> xb1, fused layer-1 gate dots
    agg_k<<<wave_blocks, 256, 0, stream>>>(xb0, xb0, rowptr, csr, d, gd0, gs0, gb, 0,
                                           yw, nw, gw + 256, gd1, gs1, xb1);
    // layer 1: gather xb1, residual xb0 (raw is FIXED across layers) -> xb2
    agg_k<<<wave_blocks, 256, 0, stream>>>(xb1, xb0, rowptr, csr, d, gd1, gs1, gb, 1,
                                           yw, nw, (const float*)nullptr,
                                           (float*)nullptr, (float*)nullptr, xb2);

    // t2 + log_softmax (bf16 x, R4-proven)
    out_k<<<(N_NODES + 63) / 64, 256, 0, stream>>>(xb2, t2_w, t2_b, outp);
}